// Round 12
// baseline (209.574 us; speedup 1.0000x reference)
//
#include <hip/hip_runtime.h>
#include <hip/hip_cooperative_groups.h>
#include <math.h>

namespace cg = cooperative_groups;

// Problem constants
#define B       200
#define V       40
#define FIN     16
#define H       128
#define NSW     12
#define NE      40
#define M       52      // NE + NSW
#define MLP_HID 1024
#define OUTD    104     // M + V + NSW
#define MLP_IN  6656    // (NSW + V) * H
#define ZDIM    144
#define ZCDIM   132
#define NCH     13      // MLP split-K chunks (r7-proven)
#define X1LD    136     // x1 LDS row stride (shorts)
#define MAXD    16      // max adjacency degree

typedef __attribute__((ext_vector_type(8))) short bf16x8;
typedef __attribute__((ext_vector_type(4))) float f32x4;

__device__ __forceinline__ float sigmoidf(float x) {
    return 1.0f / (1.0f + expf(-x));
}
__device__ __forceinline__ unsigned short f2b(float x) {  // fp32 -> bf16 RNE
    unsigned int u = __float_as_uint(x);
    u += 0x7fffu + ((u >> 16) & 1u);
    return (unsigned short)(u >> 16);
}
__device__ __forceinline__ float b2f(unsigned short s) {
    return __uint_as_float(((unsigned int)s) << 16);
}

// ================= single cooperative kernel: all 6 phases =================
// grid 256 x 512 thr; LDS union ~77 KB (2 blocks/CU capacity -> coop check OK)
__global__ __launch_bounds__(512, 2) void k_all(
        const float* __restrict__ x_mod, const int* __restrict__ ei,
        const int* __restrict__ si, const float* __restrict__ Ainc,
        const float* __restrict__ embed,
        const float* __restrict__ WU0, const float* __restrict__ WV0,
        const float* __restrict__ WA0, const float* __restrict__ WB0,
        const float* __restrict__ WC0,
        const float* __restrict__ WU1, const float* __restrict__ WV1,
        const float* __restrict__ WA1, const float* __restrict__ WB1,
        const float* __restrict__ WC1,
        const float* __restrict__ W1, const float* __restrict__ b1,
        const float* __restrict__ W2, const float* __restrict__ b2,
        unsigned short* __restrict__ W0t, unsigned short* __restrict__ Wt640,
        unsigned short* __restrict__ W2t, unsigned short* __restrict__ Abf,
        float* __restrict__ partialM, unsigned short* __restrict__ hiddenb,
        float* __restrict__ partial2, float* __restrict__ outp) {
    cg::grid_group grid = cg::this_grid();
    int bid = blockIdx.x, tid = threadIdx.x;
    int gtid = bid * 512 + tid;

    __shared__ union {
        struct {
            unsigned short xb[48 * 40];
            unsigned short uvbc[V * 512];
            unsigned short x1l[64 * X1LD];
            float gL[NSW * H];
            float sA1l[NSW * H];
            int   nbr[V][MAXD];
            int   deg[V];
        } g;                                   // 77,216 B (gnn)
        struct { unsigned short a[64 * 40]; unsigned short b[128 * 40]; } m;  // mlp/head
        struct { float o[OUTD]; float gt[M]; float vv[V]; float pfc[M]; float qfc[M]; } f;
    } lds;

    // ---------------- P0: weight prep (grid-strided) ----------------
    for (int t = gtid; t < 16384 + 81920 + 131072; t += 131072) {
        if (t < 16384) {
            int col = t >> 5, k = t & 31;
            int mm = col >> 7, hh = col & 127;
            const float* Ws = (mm == 0) ? WU0 : (mm == 1) ? WV0 : (mm == 2) ? WB0 : WC0;
            W0t[t] = (k < FIN) ? f2b(Ws[k * H + hh]) : (unsigned short)0;
        } else if (t < 16384 + 81920) {
            int o = t - 16384;
            int col = o >> 7, ff = o & 127;
            int mm = col >> 7, hh = col & 127;
            const float* Ws = (mm == 0) ? WU1 : (mm == 1) ? WV1 : (mm == 2) ? WB1
                            : (mm == 3) ? WC1 : WA1;
            Wt640[o] = f2b(Ws[ff * H + hh]);
        } else {
            int o = t - (16384 + 81920);
            int col = o >> 10, k = o & 1023;
            W2t[o] = (col < OUTD) ? f2b(W2[(size_t)k * OUTD + col]) : (unsigned short)0;
        }
    }
    grid.sync();

    // ---------------- P1: fused GNN (r7 body, blocks 0..199) ----------------
    if (bid < B) {
        int b = bid;
        unsigned short* xb   = lds.g.xb;
        unsigned short* uvbc = lds.g.uvbc;
        unsigned short* x1l  = lds.g.x1l;
        float* gL   = lds.g.gL;
        float* sA1l = lds.g.sA1l;
        int (*nbr)[MAXD] = lds.g.nbr;
        int* deg = lds.g.deg;

        int h = tid & 127, sub = tid >> 7;
        int lane = tid & 63, wv = tid >> 6;
        int lr = lane & 15, lk = lane >> 4;
        int n0w = wv * 64;

        for (int o = tid; o < 48 * 32; o += 512) {
            int r = o >> 5, k = o & 31;
            float v = (r < V && k < FIN) ? x_mod[(size_t)b * V * FIN + r * FIN + k] : 0.f;
            xb[r * 40 + k] = f2b(v);
        }
        if (tid < V) deg[tid] = 0;
        for (int o = tid; o < 12 * 128; o += 512) {
            int rr = o >> 7;
            int row = (rr < 8) ? 40 + rr : 60 + (rr - 8);
            x1l[row * X1LD + (o & 127)] = 0;
        }
        __syncthreads();

        if (tid < NE) {
            int i = ei[tid], j = ei[NE + tid];
            int p = atomicAdd(&deg[i], 1); if (p < MAXD) nbr[i][p] = j;
            int q = atomicAdd(&deg[j], 1); if (q < MAXD) nbr[j][q] = i;
        } else if (tid < NE + NSW) {
            int k = tid - NE;
            int i = si[k], j = si[NSW + k];
            int p = atomicAdd(&deg[i], 1); if (p < MAXD) nbr[i][p] = j | ((k + 1) << 8);
        }
        {
            f32x4 acc[3][4];
#pragma unroll
            for (int rf = 0; rf < 3; ++rf)
#pragma unroll
                for (int cf = 0; cf < 4; ++cf) acc[rf][cf] = (f32x4){0.f, 0.f, 0.f, 0.f};
            int kseg = lk * 8;
            bf16x8 a0 = *(const bf16x8*)&xb[lr * 40 + kseg];
            bf16x8 a1 = *(const bf16x8*)&xb[(16 + lr) * 40 + kseg];
            bf16x8 a2 = *(const bf16x8*)&xb[(32 + lr) * 40 + kseg];
#pragma unroll
            for (int cf = 0; cf < 4; ++cf) {
                bf16x8 bf = *(const bf16x8*)&W0t[(n0w + cf * 16 + lr) * 32 + kseg];
                acc[0][cf] = __builtin_amdgcn_mfma_f32_16x16x32_bf16(a0, bf, acc[0][cf], 0, 0, 0);
                acc[1][cf] = __builtin_amdgcn_mfma_f32_16x16x32_bf16(a1, bf, acc[1][cf], 0, 0, 0);
                acc[2][cf] = __builtin_amdgcn_mfma_f32_16x16x32_bf16(a2, bf, acc[2][cf], 0, 0, 0);
            }
#pragma unroll
            for (int rf = 0; rf < 3; ++rf)
#pragma unroll
                for (int cf = 0; cf < 4; ++cf)
#pragma unroll
                    for (int r = 0; r < 4; ++r) {
                        int row = rf * 16 + lk * 4 + r;
                        if (row < V) uvbc[row * 512 + n0w + cf * 16 + lr] = f2b(acc[rf][cf][r]);
                    }
        }
        __syncthreads();

        {
            float sA0 = 0.f;
#pragma unroll
            for (int f = 0; f < FIN; ++f) sA0 += embed[FIN + f] * WA0[f * H + h];
            for (int k = sub; k < NSW; k += 4) {
                int i = si[k], j = si[NSW + k];
                float e0 = sA0 + b2f(uvbc[i * 512 + 256 + h]) + b2f(uvbc[j * 512 + 384 + h]);
                gL[k * H + h] = sigmoidf(e0);
                x1l[(48 + k) * X1LD + h] = f2b(fmaxf(e0, 0.f));
            }
        }
        __syncthreads();

        for (int i = sub * 10; i < sub * 10 + 10; ++i) {
            float acc = b2f(uvbc[i * 512 + h]);
            int d = deg[i]; if (d > MAXD) d = MAXD;
            for (int p = 0; p < d; ++p) {
                int ent = nbr[i][p];
                float vv = b2f(uvbc[(ent & 255) * 512 + 128 + h]);
                int g = ent >> 8;
                if (g) vv *= gL[(g - 1) * H + h];
                acc += vv;
            }
            x1l[i * X1LD + h] = f2b(fmaxf(acc, 0.f));
        }
        __syncthreads();

        {
            f32x4 acc[3][4], accs = (f32x4){0.f, 0.f, 0.f, 0.f};
#pragma unroll
            for (int rf = 0; rf < 3; ++rf)
#pragma unroll
                for (int cf = 0; cf < 4; ++cf) acc[rf][cf] = (f32x4){0.f, 0.f, 0.f, 0.f};
#pragma unroll
            for (int kk = 0; kk < 4; ++kk) {
                int kseg = kk * 32 + lk * 8;
                bf16x8 a0 = *(const bf16x8*)&x1l[lr * X1LD + kseg];
                bf16x8 a1 = *(const bf16x8*)&x1l[(16 + lr) * X1LD + kseg];
                bf16x8 a2 = *(const bf16x8*)&x1l[(32 + lr) * X1LD + kseg];
                bf16x8 as = *(const bf16x8*)&x1l[(48 + lr) * X1LD + kseg];
#pragma unroll
                for (int cf = 0; cf < 4; ++cf) {
                    bf16x8 bf = *(const bf16x8*)&Wt640[(size_t)(n0w + cf * 16 + lr) * H + kseg];
                    acc[0][cf] = __builtin_amdgcn_mfma_f32_16x16x32_bf16(a0, bf, acc[0][cf], 0, 0, 0);
                    acc[1][cf] = __builtin_amdgcn_mfma_f32_16x16x32_bf16(a1, bf, acc[1][cf], 0, 0, 0);
                    acc[2][cf] = __builtin_amdgcn_mfma_f32_16x16x32_bf16(a2, bf, acc[2][cf], 0, 0, 0);
                }
                bf16x8 bs = *(const bf16x8*)&Wt640[(size_t)(512 + wv * 16 + lr) * H + kseg];
                accs = __builtin_amdgcn_mfma_f32_16x16x32_bf16(as, bs, accs, 0, 0, 0);
            }
#pragma unroll
            for (int rf = 0; rf < 3; ++rf)
#pragma unroll
                for (int cf = 0; cf < 4; ++cf)
#pragma unroll
                    for (int r = 0; r < 4; ++r) {
                        int row = rf * 16 + lk * 4 + r;
                        if (row < V) uvbc[row * 512 + n0w + cf * 16 + lr] = f2b(acc[rf][cf][r]);
                    }
#pragma unroll
            for (int r = 0; r < 4; ++r) {
                int sr = lk * 4 + r;
                if (sr < NSW) sA1l[sr * H + wv * 16 + lr] = accs[r];
            }
        }
        __syncthreads();

        for (int k = sub; k < NSW; k += 4) {
            int i = si[k], j = si[NSW + k];
            float e1 = sA1l[k * H + h] + b2f(uvbc[i * 512 + 256 + h]) + b2f(uvbc[j * 512 + 384 + h]);
            gL[k * H + h] = sigmoidf(e1);
            float s1 = b2f(x1l[(48 + k) * X1LD + h]);
            Abf[(size_t)b * MLP_IN + k * H + h] = f2b(s1 + fmaxf(e1, 0.f));
        }
        __syncthreads();

        for (int i = sub * 10; i < sub * 10 + 10; ++i) {
            float acc = b2f(uvbc[i * 512 + h]);
            int d = deg[i]; if (d > MAXD) d = MAXD;
            for (int p = 0; p < d; ++p) {
                int ent = nbr[i][p];
                float vv = b2f(uvbc[(ent & 255) * 512 + 128 + h]);
                int g = ent >> 8;
                if (g) vv *= gL[(g - 1) * H + h];
                acc += vv;
            }
            float x2 = b2f(x1l[i * X1LD + h]) + fmaxf(acc, 0.f);
            Abf[(size_t)b * MLP_IN + NSW * H + i * H + h] = f2b(x2);
        }
    }
    grid.sync();

    // ---------------- P2: MLP GEMM, 416 jobs, uniform 2 iters/block ----------------
    {
        unsigned short* a_lds = lds.m.a;   // 64 x 40
        unsigned short* b_lds = lds.m.b;   // 128 x 40
        int lane = tid & 63, wv = tid >> 6;
        int lr = lane & 15, lk = lane >> 4;
        int wr = (wv >> 2) * 32, wc = (wv & 3) * 32;   // 2x4 waves over 64x128

        for (int it = 0; it < 2; ++it) {
            int j = bid + it * 256;
            bool valid = (j < 416);
            int jj = valid ? j : 0;
            int z = jj >> 5;                 // 13 k-chunks of 512
            int rem = jj & 31;
            int n0 = (rem & 7) << 7;         // 8 col tiles of 128
            int m0 = (rem >> 3) << 6;        // 4 row tiles of 64
            int kbase = z << 9;

            int srow = tid >> 3, sseg = tid & 7;
            const unsigned short* gA = Abf + (size_t)(m0 + srow) * MLP_IN + kbase + sseg * 4;
            int lwsA = srow * 40 + sseg * 4;
            int bcol = tid & 127, bkg = tid >> 7;
            const float* gW = W1 + (size_t)(kbase + bkg * 8) * MLP_HID + n0 + bcol;
            int lwsB = bcol * 40 + bkg * 8;
            int a_off = (wr + lr) * 40 + lk * 8;
            int b_off = (wc + lr) * 40 + lk * 8;

            f32x4 acc00 = {0,0,0,0}, acc01 = {0,0,0,0}, acc10 = {0,0,0,0}, acc11 = {0,0,0,0};
            int2 ra = *(const int2*)gA;
            float rfv[8];
#pragma unroll
            for (int i = 0; i < 8; ++i) rfv[i] = gW[(size_t)i * MLP_HID];

            for (int kk = 0; kk < 16; ++kk) {
                *(int2*)&a_lds[lwsA] = ra;
                union { unsigned short us[8]; int4 v; } pk;
#pragma unroll
                for (int i = 0; i < 8; ++i) pk.us[i] = f2b(rfv[i]);
                *(int4*)&b_lds[lwsB] = pk.v;
                __syncthreads();
                if (kk + 1 < 16) {
                    ra = *(const int2*)(gA + (kk + 1) * 32);
                    const float* g2 = gW + (size_t)(kk + 1) * 32 * MLP_HID;
#pragma unroll
                    for (int i = 0; i < 8; ++i) rfv[i] = g2[(size_t)i * MLP_HID];
                }
                bf16x8 a0 = *(const bf16x8*)&a_lds[a_off];
                bf16x8 a1 = *(const bf16x8*)&a_lds[a_off + 16 * 40];
                bf16x8 b0 = *(const bf16x8*)&b_lds[b_off];
                bf16x8 b1 = *(const bf16x8*)&b_lds[b_off + 16 * 40];
                acc00 = __builtin_amdgcn_mfma_f32_16x16x32_bf16(a0, b0, acc00, 0, 0, 0);
                acc01 = __builtin_amdgcn_mfma_f32_16x16x32_bf16(a0, b1, acc01, 0, 0, 0);
                acc10 = __builtin_amdgcn_mfma_f32_16x16x32_bf16(a1, b0, acc10, 0, 0, 0);
                acc11 = __builtin_amdgcn_mfma_f32_16x16x32_bf16(a1, b1, acc11, 0, 0, 0);
                __syncthreads();
            }
            if (valid) {
                int crow = lk * 4, ccol = lr;
                int row0 = m0 + wr + crow, row1 = row0 + 16;
                int col0 = n0 + wc + ccol, col1 = col0 + 16;
                float* dst = partialM + (size_t)z * 256 * MLP_HID;
#pragma unroll
                for (int r = 0; r < 4; ++r) {
                    dst[(size_t)(row0 + r) * MLP_HID + col0] = acc00[r];
                    dst[(size_t)(row0 + r) * MLP_HID + col1] = acc01[r];
                    dst[(size_t)(row1 + r) * MLP_HID + col0] = acc10[r];
                    dst[(size_t)(row1 + r) * MLP_HID + col1] = acc11[r];
                }
            }
        }
    }
    grid.sync();

    // ---------------- P3: reduce partials + bias + relu -> hiddenb ----------------
    for (int t = gtid; t < 256 * MLP_HID; t += 131072) {
        float s = b1[t & (MLP_HID - 1)];
#pragma unroll
        for (int z = 0; z < NCH; ++z) s += partialM[(size_t)z * 256 * MLP_HID + t];
        hiddenb[t] = f2b(fmaxf(s, 0.f));
    }
    grid.sync();

    // ---------------- P4: head GEMM, 16 jobs (blocks 0..15) ----------------
    if (bid < 16) {
        unsigned short* a_lds = lds.m.a;   // 64 x 40
        unsigned short* b_lds = lds.m.b;   // 128 x 40
        int m0 = (bid >> 2) * 64;
        int z = bid & 3;
        int kbase = z * 256;               // NK=8
        int lane = tid & 63, wv = tid >> 6;
        int lr = lane & 15, lk = lane >> 4;
        int wr = (wv >> 2) * 32, wc = (wv & 3) * 32;

        int srow = tid >> 3, sseg = tid & 7;
        const unsigned short* gA = hiddenb + (size_t)(m0 + srow) * MLP_HID + kbase + sseg * 4;
        int lwsA = srow * 40 + sseg * 4;
        int brow = tid >> 2, bseg = tid & 3;
        const unsigned short* gB = W2t + (size_t)brow * MLP_HID + kbase + bseg * 8;
        int lwsB = brow * 40 + bseg * 8;
        int a_off = (wr + lr) * 40 + lk * 8;
        int b_off = (wc + lr) * 40 + lk * 8;

        f32x4 acc00 = {0,0,0,0}, acc01 = {0,0,0,0}, acc10 = {0,0,0,0}, acc11 = {0,0,0,0};
        int2 ra = *(const int2*)gA;
        int4 rb = *(const int4*)gB;
        for (int kk = 0; kk < 8; ++kk) {
            *(int2*)&a_lds[lwsA] = ra;
            *(int4*)&b_lds[lwsB] = rb;
            __syncthreads();
            if (kk + 1 < 8) {
                ra = *(const int2*)(gA + (kk + 1) * 32);
                rb = *(const int4*)(gB + (kk + 1) * 32);
            }
            bf16x8 a0 = *(const bf16x8*)&a_lds[a_off];
            bf16x8 a1 = *(const bf16x8*)&a_lds[a_off + 16 * 40];
            bf16x8 b0 = *(const bf16x8*)&b_lds[b_off];
            bf16x8 b1 = *(const bf16x8*)&b_lds[b_off + 16 * 40];
            acc00 = __builtin_amdgcn_mfma_f32_16x16x32_bf16(a0, b0, acc00, 0, 0, 0);
            acc01 = __builtin_amdgcn_mfma_f32_16x16x32_bf16(a0, b1, acc01, 0, 0, 0);
            acc10 = __builtin_amdgcn_mfma_f32_16x16x32_bf16(a1, b0, acc10, 0, 0, 0);
            acc11 = __builtin_amdgcn_mfma_f32_16x16x32_bf16(a1, b1, acc11, 0, 0, 0);
            __syncthreads();
        }
        int crow = lk * 4, ccol = lr;
        int row0 = m0 + wr + crow, row1 = row0 + 16;
        int col0 = wc + ccol, col1 = col0 + 16;
        float* dst = partial2 + (size_t)z * 256 * 128;
#pragma unroll
        for (int r = 0; r < 4; ++r) {
            dst[(size_t)(row0 + r) * 128 + col0] = acc00[r];
            dst[(size_t)(row0 + r) * 128 + col1] = acc01[r];
            dst[(size_t)(row1 + r) * 128 + col0] = acc10[r];
            dst[(size_t)(row1 + r) * 128 + col1] = acc11[r];
        }
    }
    grid.sync();

    // ---------------- P5: finalize + graph postprocess (blocks 0..199) ----------------
    if (bid < B) {
        int b = bid;
        float* o   = lds.f.o;
        float* gt  = lds.f.gt;
        float* vv  = lds.f.vv;
        float* pfc = lds.f.pfc;
        float* qfc = lds.f.qfc;

        if (tid < OUTD) {
            float s = b2[tid];
#pragma unroll
            for (int z = 0; z < 4; ++z) s += partial2[(size_t)z * 256 * 128 + b * 128 + tid];
            o[tid] = s;
        }
        __syncthreads();

        if (tid < M) {
            float g = (tid < M - NSW) ? 1.0f : sigmoidf(o[M + V + (tid - (M - NSW))]);
            gt[tid] = g;
            pfc[tid] = g * o[tid];
        }
        if (tid < V) vv[tid] = (tid == 0) ? 1.0f : o[M + tid];
        __syncthreads();

        if (tid < M) {
            float acc = 0.f;
            for (int xx = 0; xx < V; ++xx) acc += vv[xx] * Ainc[xx * M + tid];
            qfc[tid] = gt[tid] * acc;
        }
        __syncthreads();

        float* zb = outp + (size_t)b * ZDIM;
        if (tid < M) zb[tid] = pfc[tid];
        if (tid < V) zb[M + tid] = vv[tid];
        if (tid < M) zb[M + V + tid] = gt[tid];

        float* zcb = outp + (size_t)B * ZDIM + (size_t)b * ZCDIM;
        if (tid < M) zcb[tid] = qfc[tid];
        if (tid < V) {
            float accp = 0.f, accq = 0.f;
            for (int mm = 0; mm < M; ++mm) {
                float a = Ainc[tid * M + mm];
                accp += a * pfc[mm];
                accq += a * qfc[mm];
            }
            zcb[M + tid]     = x_mod[(size_t)(b * V + tid) * FIN + 0] + accp;
            zcb[M + V + tid] = x_mod[(size_t)(b * V + tid) * FIN + 1] + accq;
        }
    }
}

extern "C" void kernel_launch(void* const* d_in, const int* in_sizes, int n_in,
                              void* d_out, int out_size, void* d_ws, size_t ws_size,
                              hipStream_t stream) {
    const float* x_mod = (const float*)d_in[0];
    const int*   ei    = (const int*)d_in[1];
    const int*   si    = (const int*)d_in[2];
    const float* Ainc  = (const float*)d_in[3];
    const float* embed = (const float*)d_in[4];
    const float* WU0   = (const float*)d_in[5];
    const float* WV0   = (const float*)d_in[6];
    const float* WA0   = (const float*)d_in[7];
    const float* WB0   = (const float*)d_in[8];
    const float* WC0   = (const float*)d_in[9];
    const float* WU1   = (const float*)d_in[10];
    const float* WV1   = (const float*)d_in[11];
    const float* WA1   = (const float*)d_in[12];
    const float* WB1   = (const float*)d_in[13];
    const float* WC1   = (const float*)d_in[14];
    const float* W1    = (const float*)d_in[15];
    const float* b1    = (const float*)d_in[16];
    const float* W2    = (const float*)d_in[17];
    const float* b2    = (const float*)d_in[18];
    float* out = (float*)d_out;

    // Workspace layout (byte offsets), ~18 MB
    char* ws = (char*)d_ws;
    unsigned short* W0t      = (unsigned short*)(ws + 0);          //    32,768
    unsigned short* Wt640    = (unsigned short*)(ws + 32768);      //   163,840
    unsigned short* W2t      = (unsigned short*)(ws + 196608);     //   262,144
    unsigned short* Abf      = (unsigned short*)(ws + 458752);     // 3,407,872 (rows >=200 stale, benign)
    float*          partialM = (float*)(ws + 3866624);             // 13,631,488
    unsigned short* hiddenb  = (unsigned short*)(ws + 17498112);   //   524,288
    float*          partial2 = (float*)(ws + 18022400);            //   524,288

    void* kargs[] = {
        (void*)&x_mod, (void*)&ei, (void*)&si, (void*)&Ainc, (void*)&embed,
        (void*)&WU0, (void*)&WV0, (void*)&WA0, (void*)&WB0, (void*)&WC0,
        (void*)&WU1, (void*)&WV1, (void*)&WA1, (void*)&WB1, (void*)&WC1,
        (void*)&W1, (void*)&b1, (void*)&W2, (void*)&b2,
        (void*)&W0t, (void*)&Wt640, (void*)&W2t, (void*)&Abf,
        (void*)&partialM, (void*)&hiddenb, (void*)&partial2, (void*)&out
    };
    hipLaunchCooperativeKernel((const void*)k_all, dim3(256), dim3(512),
                               kargs, 0, stream);
}

// Round 13
// 58.099 us; speedup vs baseline: 3.6072x; 3.6072x over previous
//
#include <hip/hip_runtime.h>
#include <math.h>

// Problem constants
#define B       200
#define V       40
#define FIN     16
#define H       128
#define NSW     12
#define NE      40
#define M       52      // NE + NSW
#define MLP_HID 1024
#define OUTD    104     // M + V + NSW
#define MLP_IN  6656    // (NSW + V) * H
#define ZDIM    144
#define ZCDIM   132
#define NCH     13      // MLP split-K chunks (r7-proven)
#define X1LD    136     // x1 LDS row stride (shorts)
#define MAXD    16      // max adjacency degree

typedef __attribute__((ext_vector_type(8))) short bf16x8;
typedef __attribute__((ext_vector_type(4))) float f32x4;

__device__ __forceinline__ float sigmoidf(float x) {
    return 1.0f / (1.0f + expf(-x));
}
__device__ __forceinline__ unsigned short f2b(float x) {  // fp32 -> bf16 RNE
    unsigned int u = __float_as_uint(x);
    u += 0x7fffu + ((u >> 16) & 1u);
    return (unsigned short)(u >> 16);
}
__device__ __forceinline__ float b2f(unsigned short s) {
    return __uint_as_float(((unsigned int)s) << 16);
}

// ---------------- weight prep (small mats; W1 handled inside k_mlp) [r7 verbatim] ----------------
__global__ __launch_bounds__(256) void k_prep(
        const float* __restrict__ WU0, const float* __restrict__ WV0,
        const float* __restrict__ WB0, const float* __restrict__ WC0,
        const float* __restrict__ WU1, const float* __restrict__ WV1,
        const float* __restrict__ WB1, const float* __restrict__ WC1,
        const float* __restrict__ WA1, const float* __restrict__ W2,
        unsigned short* __restrict__ W0t, unsigned short* __restrict__ Wt640,
        unsigned short* __restrict__ W2t) {
    int bx = blockIdx.x, tid = threadIdx.x;
    if (bx < 64) {
        int o0 = bx * 2048 + tid * 8;
#pragma unroll
        for (int i = 0; i < 8; ++i) {
            int o = o0 + i; int col = o >> 10, k = o & 1023;
            W2t[o] = (col < OUTD) ? f2b(W2[(size_t)k * OUTD + col]) : (unsigned short)0;
        }
    } else if (bx < 104) {
        int o0 = (bx - 64) * 2048 + tid * 8;
#pragma unroll
        for (int i = 0; i < 8; ++i) {
            int o = o0 + i; int col = o >> 7, f = o & 127;
            int m = col >> 7, hh = col & 127;
            const float* Ws = (m == 0) ? WU1 : (m == 1) ? WV1 : (m == 2) ? WB1
                            : (m == 3) ? WC1 : WA1;
            Wt640[o] = f2b(Ws[f * H + hh]);
        }
    } else {
        int o0 = (bx - 104) * 2048 + tid * 8;
#pragma unroll
        for (int i = 0; i < 8; ++i) {
            int o = o0 + i; int col = o >> 5, k = o & 31;
            int m = col >> 7, hh = col & 127;
            const float* Ws = (m == 0) ? WU0 : (m == 1) ? WV0 : (m == 2) ? WB0 : WC0;
            W0t[o] = (k < FIN) ? f2b(Ws[k * H + hh]) : (unsigned short)0;
        }
    }
}

// ---------------- fully fused GNN [r7 verbatim] ----------------
__global__ __launch_bounds__(512) void k_gnn(const float* __restrict__ x,
        const int* __restrict__ ei, const int* __restrict__ si,
        const float* __restrict__ embed, const float* __restrict__ WA0,
        const unsigned short* __restrict__ W0t,
        const unsigned short* __restrict__ Wt640,
        unsigned short* __restrict__ Abf) {
    int b = blockIdx.x, tid = threadIdx.x;
    __shared__ unsigned short xb[48 * 40];
    __shared__ unsigned short uvbc[V * 512];
    __shared__ unsigned short x1l[64 * X1LD];
    __shared__ float gL[NSW * H];
    __shared__ float sA1l[NSW * H];
    __shared__ int   nbr[V][MAXD];
    __shared__ int   deg[V];

    int h = tid & 127, sub = tid >> 7;
    int lane = tid & 63, wv = tid >> 6;
    int lr = lane & 15, lk = lane >> 4;
    int n0w = wv * 64;

    for (int o = tid; o < 48 * 32; o += 512) {
        int r = o >> 5, k = o & 31;
        float v = (r < V && k < FIN) ? x[(size_t)b * V * FIN + r * FIN + k] : 0.f;
        xb[r * 40 + k] = f2b(v);
    }
    if (tid < V) deg[tid] = 0;
    for (int o = tid; o < 12 * 128; o += 512) {
        int rr = o >> 7;
        int row = (rr < 8) ? 40 + rr : 60 + (rr - 8);
        x1l[row * X1LD + (o & 127)] = 0;
    }
    __syncthreads();

    if (tid < NE) {
        int i = ei[tid], j = ei[NE + tid];
        int p = atomicAdd(&deg[i], 1); if (p < MAXD) nbr[i][p] = j;
        int q = atomicAdd(&deg[j], 1); if (q < MAXD) nbr[j][q] = i;
    } else if (tid < NE + NSW) {
        int k = tid - NE;
        int i = si[k], j = si[NSW + k];
        int p = atomicAdd(&deg[i], 1); if (p < MAXD) nbr[i][p] = j | ((k + 1) << 8);
    }
    {
        f32x4 acc[3][4];
#pragma unroll
        for (int rf = 0; rf < 3; ++rf)
#pragma unroll
            for (int cf = 0; cf < 4; ++cf) acc[rf][cf] = (f32x4){0.f, 0.f, 0.f, 0.f};
        int kseg = lk * 8;
        bf16x8 a0 = *(const bf16x8*)&xb[lr * 40 + kseg];
        bf16x8 a1 = *(const bf16x8*)&xb[(16 + lr) * 40 + kseg];
        bf16x8 a2 = *(const bf16x8*)&xb[(32 + lr) * 40 + kseg];
#pragma unroll
        for (int cf = 0; cf < 4; ++cf) {
            bf16x8 bf = *(const bf16x8*)&W0t[(n0w + cf * 16 + lr) * 32 + kseg];
            acc[0][cf] = __builtin_amdgcn_mfma_f32_16x16x32_bf16(a0, bf, acc[0][cf], 0, 0, 0);
            acc[1][cf] = __builtin_amdgcn_mfma_f32_16x16x32_bf16(a1, bf, acc[1][cf], 0, 0, 0);
            acc[2][cf] = __builtin_amdgcn_mfma_f32_16x16x32_bf16(a2, bf, acc[2][cf], 0, 0, 0);
        }
#pragma unroll
        for (int rf = 0; rf < 3; ++rf)
#pragma unroll
            for (int cf = 0; cf < 4; ++cf)
#pragma unroll
                for (int r = 0; r < 4; ++r) {
                    int row = rf * 16 + lk * 4 + r;
                    if (row < V) uvbc[row * 512 + n0w + cf * 16 + lr] = f2b(acc[rf][cf][r]);
                }
    }
    __syncthreads();

    {
        float sA0 = 0.f;
#pragma unroll
        for (int f = 0; f < FIN; ++f) sA0 += embed[FIN + f] * WA0[f * H + h];
        for (int k = sub; k < NSW; k += 4) {
            int i = si[k], j = si[NSW + k];
            float e0 = sA0 + b2f(uvbc[i * 512 + 256 + h]) + b2f(uvbc[j * 512 + 384 + h]);
            gL[k * H + h] = sigmoidf(e0);
            x1l[(48 + k) * X1LD + h] = f2b(fmaxf(e0, 0.f));
        }
    }
    __syncthreads();

    for (int i = sub * 10; i < sub * 10 + 10; ++i) {
        float acc = b2f(uvbc[i * 512 + h]);
        int d = deg[i]; if (d > MAXD) d = MAXD;
        for (int p = 0; p < d; ++p) {
            int ent = nbr[i][p];
            float vv = b2f(uvbc[(ent & 255) * 512 + 128 + h]);
            int g = ent >> 8;
            if (g) vv *= gL[(g - 1) * H + h];
            acc += vv;
        }
        x1l[i * X1LD + h] = f2b(fmaxf(acc, 0.f));
    }
    __syncthreads();

    {
        f32x4 acc[3][4], accs = (f32x4){0.f, 0.f, 0.f, 0.f};
#pragma unroll
        for (int rf = 0; rf < 3; ++rf)
#pragma unroll
            for (int cf = 0; cf < 4; ++cf) acc[rf][cf] = (f32x4){0.f, 0.f, 0.f, 0.f};
#pragma unroll
        for (int kk = 0; kk < 4; ++kk) {
            int kseg = kk * 32 + lk * 8;
            bf16x8 a0 = *(const bf16x8*)&x1l[lr * X1LD + kseg];
            bf16x8 a1 = *(const bf16x8*)&x1l[(16 + lr) * X1LD + kseg];
            bf16x8 a2 = *(const bf16x8*)&x1l[(32 + lr) * X1LD + kseg];
            bf16x8 as = *(const bf16x8*)&x1l[(48 + lr) * X1LD + kseg];
#pragma unroll
            for (int cf = 0; cf < 4; ++cf) {
                bf16x8 bf = *(const bf16x8*)&Wt640[(size_t)(n0w + cf * 16 + lr) * H + kseg];
                acc[0][cf] = __builtin_amdgcn_mfma_f32_16x16x32_bf16(a0, bf, acc[0][cf], 0, 0, 0);
                acc[1][cf] = __builtin_amdgcn_mfma_f32_16x16x32_bf16(a1, bf, acc[1][cf], 0, 0, 0);
                acc[2][cf] = __builtin_amdgcn_mfma_f32_16x16x32_bf16(a2, bf, acc[2][cf], 0, 0, 0);
            }
            bf16x8 bs = *(const bf16x8*)&Wt640[(size_t)(512 + wv * 16 + lr) * H + kseg];
            accs = __builtin_amdgcn_mfma_f32_16x16x32_bf16(as, bs, accs, 0, 0, 0);
        }
#pragma unroll
        for (int rf = 0; rf < 3; ++rf)
#pragma unroll
            for (int cf = 0; cf < 4; ++cf)
#pragma unroll
                for (int r = 0; r < 4; ++r) {
                    int row = rf * 16 + lk * 4 + r;
                    if (row < V) uvbc[row * 512 + n0w + cf * 16 + lr] = f2b(acc[rf][cf][r]);
                }
#pragma unroll
        for (int r = 0; r < 4; ++r) {
            int sr = lk * 4 + r;
            if (sr < NSW) sA1l[sr * H + wv * 16 + lr] = accs[r];
        }
    }
    __syncthreads();

    for (int k = sub; k < NSW; k += 4) {
        int i = si[k], j = si[NSW + k];
        float e1 = sA1l[k * H + h] + b2f(uvbc[i * 512 + 256 + h]) + b2f(uvbc[j * 512 + 384 + h]);
        gL[k * H + h] = sigmoidf(e1);
        float s1 = b2f(x1l[(48 + k) * X1LD + h]);
        Abf[(size_t)b * MLP_IN + k * H + h] = f2b(s1 + fmaxf(e1, 0.f));
    }
    __syncthreads();

    for (int i = sub * 10; i < sub * 10 + 10; ++i) {
        float acc = b2f(uvbc[i * 512 + h]);
        int d = deg[i]; if (d > MAXD) d = MAXD;
        for (int p = 0; p < d; ++p) {
            int ent = nbr[i][p];
            float vv = b2f(uvbc[(ent & 255) * 512 + 128 + h]);
            int g = ent >> 8;
            if (g) vv *= gL[(g - 1) * H + h];
            acc += vv;
        }
        float x2 = b2f(x1l[i * X1LD + h]) + fmaxf(acc, 0.f);
        Abf[(size_t)b * MLP_IN + NSW * H + i * H + h] = f2b(x2);
    }
}

// ---------------- MLP GEMM: fused W1 transpose+convert [r7 verbatim] ----------------
// partial[z][m][n] = Abf[m][k-chunk] @ W1[k-chunk][n]; grid(16,4,NCH), nk=16
__global__ __launch_bounds__(256) void k_mlp(const unsigned short* __restrict__ A,
        const float* __restrict__ W1, float* __restrict__ partial) {
    const int NK = 16;
    int tid = threadIdx.x;
    int lane = tid & 63, wvv = tid >> 6;
    int wr = (wvv >> 1) * 32, wc = (wvv & 1) * 32;
    int n0 = blockIdx.x * 64, m0 = blockIdx.y * 64;
    int kbase = blockIdx.z * NK * 32;

    __shared__ __align__(16) unsigned short a_lds[64 * 40];
    __shared__ __align__(16) unsigned short b_lds[64 * 40];

    f32x4 acc00 = {0,0,0,0}, acc01 = {0,0,0,0}, acc10 = {0,0,0,0}, acc11 = {0,0,0,0};

    int srow = tid >> 2, sseg = tid & 3;
    const int4* gA = (const int4*)(A + (size_t)(m0 + srow) * MLP_IN + kbase + sseg * 8);
    int lwsA = srow * 40 + sseg * 8;

    int bcol = tid & 63, bkg = tid >> 6;
    const float* gW = W1 + (size_t)(kbase + bkg * 8) * MLP_HID + n0 + bcol;
    int lwsB = bcol * 40 + bkg * 8;

    int a_off = (wr + (lane & 15)) * 40 + (lane >> 4) * 8;
    int b_off = (wc + (lane & 15)) * 40 + (lane >> 4) * 8;

    int4 ra = gA[0];
    float rfv[8];
#pragma unroll
    for (int i = 0; i < 8; ++i) rfv[i] = gW[(size_t)i * MLP_HID];

    for (int kk = 0; kk < NK; ++kk) {
        *(int4*)&a_lds[lwsA] = ra;
        union { unsigned short us[8]; int4 v; } pk;
#pragma unroll
        for (int i = 0; i < 8; ++i) pk.us[i] = f2b(rfv[i]);
        *(int4*)&b_lds[lwsB] = pk.v;
        __syncthreads();
        if (kk + 1 < NK) {
            ra = gA[(kk + 1) * 4];
            const float* g2 = gW + (size_t)(kk + 1) * 32 * MLP_HID;
#pragma unroll
            for (int i = 0; i < 8; ++i) rfv[i] = g2[(size_t)i * MLP_HID];
        }
        bf16x8 a0 = *(const bf16x8*)&a_lds[a_off];
        bf16x8 a1 = *(const bf16x8*)&a_lds[a_off + 16 * 40];
        bf16x8 b0 = *(const bf16x8*)&b_lds[b_off];
        bf16x8 b1 = *(const bf16x8*)&b_lds[b_off + 16 * 40];
        acc00 = __builtin_amdgcn_mfma_f32_16x16x32_bf16(a0, b0, acc00, 0, 0, 0);
        acc01 = __builtin_amdgcn_mfma_f32_16x16x32_bf16(a0, b1, acc01, 0, 0, 0);
        acc10 = __builtin_amdgcn_mfma_f32_16x16x32_bf16(a1, b0, acc10, 0, 0, 0);
        acc11 = __builtin_amdgcn_mfma_f32_16x16x32_bf16(a1, b1, acc11, 0, 0, 0);
        __syncthreads();
    }

    int crow = (lane >> 4) * 4, ccol = lane & 15;
    int row0 = m0 + wr + crow, row1 = row0 + 16;
    int col0 = n0 + wc + ccol, col1 = col0 + 16;
    float* dst = partial + (size_t)blockIdx.z * 256 * MLP_HID;
#pragma unroll
    for (int r = 0; r < 4; ++r) {
        dst[(size_t)(row0 + r) * MLP_HID + col0] = acc00[r];
        dst[(size_t)(row0 + r) * MLP_HID + col1] = acc01[r];
        dst[(size_t)(row1 + r) * MLP_HID + col0] = acc10[r];
        dst[(size_t)(row1 + r) * MLP_HID + col1] = acc11[r];
    }
}

// ---------------- fused tail: mred + head GEMV + postprocess (per batch) ----------------
// 200 blocks x 256 thr. Replaces k_mred + head k_gemm + k_fin (saves 2 launches,
// hiddenb & partial2 round-trips). GEMV uses row-major W2t (sequential 16B/thread,
// L2-resident) — NOT r4's strided-scalar trap.
__global__ __launch_bounds__(256) void k_fin2(const float* __restrict__ partialM,
        const float* __restrict__ b1, const unsigned short* __restrict__ W2t,
        const float* __restrict__ b2, const float* __restrict__ Ainc,
        const float* __restrict__ x_mod, float* __restrict__ outp) {
    int b = blockIdx.x;
    int tid = threadIdx.x;
    __shared__ __align__(16) unsigned short hid[MLP_HID];   // 2 KB bf16
    __shared__ float oacc[OUTD][2];
    __shared__ float o[OUTD];
    __shared__ float gt[M], vv[V], pfc[M], qfc[M];

    // stage 1: split-K reduce + bias + relu -> hid (bf16)
    for (int c = tid; c < MLP_HID; c += 256) {
        float s = b1[c];
        const float* p = partialM + (size_t)b * MLP_HID + c;
#pragma unroll
        for (int z = 0; z < NCH; ++z) s += p[(size_t)z * 256 * MLP_HID];
        hid[c] = f2b(fmaxf(s, 0.f));
    }
    __syncthreads();

    // stage 2: GEMV o[col] = sum_k hid[k] * W2t[col][k]; 208 threads, K split in 2
    if (tid < 2 * OUTD) {
        int col = tid >> 1, half = tid & 1;
        const unsigned short* wrow = W2t + (size_t)col * MLP_HID + half * 512;
        const unsigned short* hrow = hid + half * 512;
        float acc = 0.f;
#pragma unroll 4
        for (int k8 = 0; k8 < 64; ++k8) {
            bf16x8 hv = *(const bf16x8*)&hrow[k8 * 8];
            bf16x8 wv = *(const bf16x8*)&wrow[k8 * 8];
#pragma unroll
            for (int i = 0; i < 8; ++i)
                acc += b2f((unsigned short)hv[i]) * b2f((unsigned short)wv[i]);
        }
        oacc[col][half] = acc;
    }
    __syncthreads();
    if (tid < OUTD) o[tid] = b2[tid] + oacc[tid][0] + oacc[tid][1];
    __syncthreads();

    // stage 3: graph postprocess (r7 k_fin body)
    if (tid < M) {
        float g = (tid < M - NSW) ? 1.0f : sigmoidf(o[M + V + (tid - (M - NSW))]);
        gt[tid] = g;
        pfc[tid] = g * o[tid];
    }
    if (tid < V) vv[tid] = (tid == 0) ? 1.0f : o[M + tid];
    __syncthreads();

    if (tid < M) {
        float acc = 0.f;
        for (int xx = 0; xx < V; ++xx) acc += vv[xx] * Ainc[xx * M + tid];
        qfc[tid] = gt[tid] * acc;
    }
    __syncthreads();

    float* zb = outp + (size_t)b * ZDIM;
    if (tid < M) zb[tid] = pfc[tid];
    if (tid < V) zb[M + tid] = vv[tid];
    if (tid < M) zb[M + V + tid] = gt[tid];

    float* zcb = outp + (size_t)B * ZDIM + (size_t)b * ZCDIM;
    if (tid < M) zcb[tid] = qfc[tid];
    if (tid < V) {
        float accp = 0.f, accq = 0.f;
        for (int mm = 0; mm < M; ++mm) {
            float a = Ainc[tid * M + mm];
            accp += a * pfc[mm];
            accq += a * qfc[mm];
        }
        zcb[M + tid]     = x_mod[(size_t)(b * V + tid) * FIN + 0] + accp;
        zcb[M + V + tid] = x_mod[(size_t)(b * V + tid) * FIN + 1] + accq;
    }
}

extern "C" void kernel_launch(void* const* d_in, const int* in_sizes, int n_in,
                              void* d_out, int out_size, void* d_ws, size_t ws_size,
                              hipStream_t stream) {
    const float* x_mod = (const float*)d_in[0];
    const int*   ei    = (const int*)d_in[1];
    const int*   si    = (const int*)d_in[2];
    const float* Ainc  = (const float*)d_in[3];
    const float* embed = (const float*)d_in[4];
    const float* WU0   = (const float*)d_in[5];
    const float* WV0   = (const float*)d_in[6];
    const float* WA0   = (const float*)d_in[7];
    const float* WB0   = (const float*)d_in[8];
    const float* WC0   = (const float*)d_in[9];
    const float* WU1   = (const float*)d_in[10];
    const float* WV1   = (const float*)d_in[11];
    const float* WA1   = (const float*)d_in[12];
    const float* WB1   = (const float*)d_in[13];
    const float* WC1   = (const float*)d_in[14];
    const float* W1    = (const float*)d_in[15];
    const float* b1    = (const float*)d_in[16];
    const float* W2    = (const float*)d_in[17];
    const float* b2    = (const float*)d_in[18];
    float* out = (float*)d_out;

    // Workspace layout (byte offsets), ~17.5 MB
    char* ws = (char*)d_ws;
    unsigned short* W0t      = (unsigned short*)(ws + 0);          //    32,768
    unsigned short* Wt640    = (unsigned short*)(ws + 32768);      //   163,840
    unsigned short* W2t      = (unsigned short*)(ws + 196608);     //   262,144
    unsigned short* Abf      = (unsigned short*)(ws + 458752);     // 3,407,872 (rows >=200 stale, benign)
    float*          partialM = (float*)(ws + 3866624);             // 13,631,488

    // 1. small weight prep (W0t, Wt640, W2t)
    k_prep<<<112, 256, 0, stream>>>(WU0, WV0, WB0, WC0, WU1, WV1, WB1, WC1, WA1, W2,
                                    W0t, Wt640, W2t);
    // 2. fully fused GNN (both layers, MFMA projections) -> Abf
    k_gnn<<<B, 512, 0, stream>>>(x_mod, ei, si, embed, WA0, W0t, Wt640, Abf);
    // 3. MLP hidden: (256x6656) @ W1 (f32, on-the-fly transpose), split-K=13 [r7 exact]
    k_mlp<<<dim3(16, 4, NCH), 256, 0, stream>>>(Abf, W1, partialM);
    // 4. fused tail: reduce + bias/relu + W2 GEMV + graph postprocess
    k_fin2<<<B, 256, 0, stream>>>(partialM, b1, W2t, b2, Ainc, x_mod, out);
}

// Round 14
// 54.915 us; speedup vs baseline: 3.8163x; 1.0580x over previous
//
#include <hip/hip_runtime.h>
#include <math.h>

// Problem constants
#define B       200
#define V       40
#define FIN     16
#define H       128
#define NSW     12
#define NE      40
#define M       52      // NE + NSW
#define MLP_HID 1024
#define OUTD    104     // M + V + NSW
#define MLP_IN  6656    // (NSW + V) * H
#define ZDIM    144
#define ZCDIM   132
#define NCH     13      // MLP split-K chunks (r7-proven)
#define X1LD    136     // x1 LDS row stride (shorts)
#define MAXD    16      // max adjacency degree

typedef __attribute__((ext_vector_type(8))) short bf16x8;
typedef __attribute__((ext_vector_type(4))) float f32x4;

__device__ __forceinline__ float sigmoidf(float x) {
    return 1.0f / (1.0f + expf(-x));
}
__device__ __forceinline__ unsigned short f2b(float x) {  // fp32 -> bf16 RNE
    unsigned int u = __float_as_uint(x);
    u += 0x7fffu + ((u >> 16) & 1u);
    return (unsigned short)(u >> 16);
}
__device__ __forceinline__ float b2f(unsigned short s) {
    return __uint_as_float(((unsigned int)s) << 16);
}

// ---------------- weight prep (small mats; W1 handled inside k_mlp) [r7 verbatim] ----------------
__global__ __launch_bounds__(256) void k_prep(
        const float* __restrict__ WU0, const float* __restrict__ WV0,
        const float* __restrict__ WB0, const float* __restrict__ WC0,
        const float* __restrict__ WU1, const float* __restrict__ WV1,
        const float* __restrict__ WB1, const float* __restrict__ WC1,
        const float* __restrict__ WA1, const float* __restrict__ W2,
        unsigned short* __restrict__ W0t, unsigned short* __restrict__ Wt640,
        unsigned short* __restrict__ W2t) {
    int bx = blockIdx.x, tid = threadIdx.x;
    if (bx < 64) {
        int o0 = bx * 2048 + tid * 8;
#pragma unroll
        for (int i = 0; i < 8; ++i) {
            int o = o0 + i; int col = o >> 10, k = o & 1023;
            W2t[o] = (col < OUTD) ? f2b(W2[(size_t)k * OUTD + col]) : (unsigned short)0;
        }
    } else if (bx < 104) {
        int o0 = (bx - 64) * 2048 + tid * 8;
#pragma unroll
        for (int i = 0; i < 8; ++i) {
            int o = o0 + i; int col = o >> 7, f = o & 127;
            int m = col >> 7, hh = col & 127;
            const float* Ws = (m == 0) ? WU1 : (m == 1) ? WV1 : (m == 2) ? WB1
                            : (m == 3) ? WC1 : WA1;
            Wt640[o] = f2b(Ws[f * H + hh]);
        }
    } else {
        int o0 = (bx - 104) * 2048 + tid * 8;
#pragma unroll
        for (int i = 0; i < 8; ++i) {
            int o = o0 + i; int col = o >> 5, k = o & 31;
            int m = col >> 7, hh = col & 127;
            const float* Ws = (m == 0) ? WU0 : (m == 1) ? WV0 : (m == 2) ? WB0 : WC0;
            W0t[o] = (k < FIN) ? f2b(Ws[k * H + hh]) : (unsigned short)0;
        }
    }
}

// ---------------- fully fused GNN [r7 verbatim] ----------------
__global__ __launch_bounds__(512) void k_gnn(const float* __restrict__ x,
        const int* __restrict__ ei, const int* __restrict__ si,
        const float* __restrict__ embed, const float* __restrict__ WA0,
        const unsigned short* __restrict__ W0t,
        const unsigned short* __restrict__ Wt640,
        unsigned short* __restrict__ Abf) {
    int b = blockIdx.x, tid = threadIdx.x;
    __shared__ unsigned short xb[48 * 40];
    __shared__ unsigned short uvbc[V * 512];
    __shared__ unsigned short x1l[64 * X1LD];
    __shared__ float gL[NSW * H];
    __shared__ float sA1l[NSW * H];
    __shared__ int   nbr[V][MAXD];
    __shared__ int   deg[V];

    int h = tid & 127, sub = tid >> 7;
    int lane = tid & 63, wv = tid >> 6;
    int lr = lane & 15, lk = lane >> 4;
    int n0w = wv * 64;

    for (int o = tid; o < 48 * 32; o += 512) {
        int r = o >> 5, k = o & 31;
        float v = (r < V && k < FIN) ? x[(size_t)b * V * FIN + r * FIN + k] : 0.f;
        xb[r * 40 + k] = f2b(v);
    }
    if (tid < V) deg[tid] = 0;
    for (int o = tid; o < 12 * 128; o += 512) {
        int rr = o >> 7;
        int row = (rr < 8) ? 40 + rr : 60 + (rr - 8);
        x1l[row * X1LD + (o & 127)] = 0;
    }
    __syncthreads();

    if (tid < NE) {
        int i = ei[tid], j = ei[NE + tid];
        int p = atomicAdd(&deg[i], 1); if (p < MAXD) nbr[i][p] = j;
        int q = atomicAdd(&deg[j], 1); if (q < MAXD) nbr[j][q] = i;
    } else if (tid < NE + NSW) {
        int k = tid - NE;
        int i = si[k], j = si[NSW + k];
        int p = atomicAdd(&deg[i], 1); if (p < MAXD) nbr[i][p] = j | ((k + 1) << 8);
    }
    {
        f32x4 acc[3][4];
#pragma unroll
        for (int rf = 0; rf < 3; ++rf)
#pragma unroll
            for (int cf = 0; cf < 4; ++cf) acc[rf][cf] = (f32x4){0.f, 0.f, 0.f, 0.f};
        int kseg = lk * 8;
        bf16x8 a0 = *(const bf16x8*)&xb[lr * 40 + kseg];
        bf16x8 a1 = *(const bf16x8*)&xb[(16 + lr) * 40 + kseg];
        bf16x8 a2 = *(const bf16x8*)&xb[(32 + lr) * 40 + kseg];
#pragma unroll
        for (int cf = 0; cf < 4; ++cf) {
            bf16x8 bf = *(const bf16x8*)&W0t[(n0w + cf * 16 + lr) * 32 + kseg];
            acc[0][cf] = __builtin_amdgcn_mfma_f32_16x16x32_bf16(a0, bf, acc[0][cf], 0, 0, 0);
            acc[1][cf] = __builtin_amdgcn_mfma_f32_16x16x32_bf16(a1, bf, acc[1][cf], 0, 0, 0);
            acc[2][cf] = __builtin_amdgcn_mfma_f32_16x16x32_bf16(a2, bf, acc[2][cf], 0, 0, 0);
        }
#pragma unroll
        for (int rf = 0; rf < 3; ++rf)
#pragma unroll
            for (int cf = 0; cf < 4; ++cf)
#pragma unroll
                for (int r = 0; r < 4; ++r) {
                    int row = rf * 16 + lk * 4 + r;
                    if (row < V) uvbc[row * 512 + n0w + cf * 16 + lr] = f2b(acc[rf][cf][r]);
                }
    }
    __syncthreads();

    {
        float sA0 = 0.f;
#pragma unroll
        for (int f = 0; f < FIN; ++f) sA0 += embed[FIN + f] * WA0[f * H + h];
        for (int k = sub; k < NSW; k += 4) {
            int i = si[k], j = si[NSW + k];
            float e0 = sA0 + b2f(uvbc[i * 512 + 256 + h]) + b2f(uvbc[j * 512 + 384 + h]);
            gL[k * H + h] = sigmoidf(e0);
            x1l[(48 + k) * X1LD + h] = f2b(fmaxf(e0, 0.f));
        }
    }
    __syncthreads();

    for (int i = sub * 10; i < sub * 10 + 10; ++i) {
        float acc = b2f(uvbc[i * 512 + h]);
        int d = deg[i]; if (d > MAXD) d = MAXD;
        for (int p = 0; p < d; ++p) {
            int ent = nbr[i][p];
            float vv = b2f(uvbc[(ent & 255) * 512 + 128 + h]);
            int g = ent >> 8;
            if (g) vv *= gL[(g - 1) * H + h];
            acc += vv;
        }
        x1l[i * X1LD + h] = f2b(fmaxf(acc, 0.f));
    }
    __syncthreads();

    {
        f32x4 acc[3][4], accs = (f32x4){0.f, 0.f, 0.f, 0.f};
#pragma unroll
        for (int rf = 0; rf < 3; ++rf)
#pragma unroll
            for (int cf = 0; cf < 4; ++cf) acc[rf][cf] = (f32x4){0.f, 0.f, 0.f, 0.f};
#pragma unroll
        for (int kk = 0; kk < 4; ++kk) {
            int kseg = kk * 32 + lk * 8;
            bf16x8 a0 = *(const bf16x8*)&x1l[lr * X1LD + kseg];
            bf16x8 a1 = *(const bf16x8*)&x1l[(16 + lr) * X1LD + kseg];
            bf16x8 a2 = *(const bf16x8*)&x1l[(32 + lr) * X1LD + kseg];
            bf16x8 as = *(const bf16x8*)&x1l[(48 + lr) * X1LD + kseg];
#pragma unroll
            for (int cf = 0; cf < 4; ++cf) {
                bf16x8 bf = *(const bf16x8*)&Wt640[(size_t)(n0w + cf * 16 + lr) * H + kseg];
                acc[0][cf] = __builtin_amdgcn_mfma_f32_16x16x32_bf16(a0, bf, acc[0][cf], 0, 0, 0);
                acc[1][cf] = __builtin_amdgcn_mfma_f32_16x16x32_bf16(a1, bf, acc[1][cf], 0, 0, 0);
                acc[2][cf] = __builtin_amdgcn_mfma_f32_16x16x32_bf16(a2, bf, acc[2][cf], 0, 0, 0);
            }
            bf16x8 bs = *(const bf16x8*)&Wt640[(size_t)(512 + wv * 16 + lr) * H + kseg];
            accs = __builtin_amdgcn_mfma_f32_16x16x32_bf16(as, bs, accs, 0, 0, 0);
        }
#pragma unroll
        for (int rf = 0; rf < 3; ++rf)
#pragma unroll
            for (int cf = 0; cf < 4; ++cf)
#pragma unroll
                for (int r = 0; r < 4; ++r) {
                    int row = rf * 16 + lk * 4 + r;
                    if (row < V) uvbc[row * 512 + n0w + cf * 16 + lr] = f2b(acc[rf][cf][r]);
                }
#pragma unroll
        for (int r = 0; r < 4; ++r) {
            int sr = lk * 4 + r;
            if (sr < NSW) sA1l[sr * H + wv * 16 + lr] = accs[r];
        }
    }
    __syncthreads();

    for (int k = sub; k < NSW; k += 4) {
        int i = si[k], j = si[NSW + k];
        float e1 = sA1l[k * H + h] + b2f(uvbc[i * 512 + 256 + h]) + b2f(uvbc[j * 512 + 384 + h]);
        gL[k * H + h] = sigmoidf(e1);
        float s1 = b2f(x1l[(48 + k) * X1LD + h]);
        Abf[(size_t)b * MLP_IN + k * H + h] = f2b(s1 + fmaxf(e1, 0.f));
    }
    __syncthreads();

    for (int i = sub * 10; i < sub * 10 + 10; ++i) {
        float acc = b2f(uvbc[i * 512 + h]);
        int d = deg[i]; if (d > MAXD) d = MAXD;
        for (int p = 0; p < d; ++p) {
            int ent = nbr[i][p];
            float vv = b2f(uvbc[(ent & 255) * 512 + 128 + h]);
            int g = ent >> 8;
            if (g) vv *= gL[(g - 1) * H + h];
            acc += vv;
        }
        float x2 = b2f(x1l[i * X1LD + h]) + fmaxf(acc, 0.f);
        Abf[(size_t)b * MLP_IN + NSW * H + i * H + h] = f2b(x2);
    }
}

// ---------------- MLP GEMM [r7 structure; DELTA: bf16 partial store] ----------------
// partial[z][m][n] (bf16) = Abf[m][k-chunk] @ W1[k-chunk][n]; grid(16,4,NCH), nk=16
__global__ __launch_bounds__(256) void k_mlp(const unsigned short* __restrict__ A,
        const float* __restrict__ W1, unsigned short* __restrict__ partial) {
    const int NK = 16;
    int tid = threadIdx.x;
    int lane = tid & 63, wvv = tid >> 6;
    int wr = (wvv >> 1) * 32, wc = (wvv & 1) * 32;
    int n0 = blockIdx.x * 64, m0 = blockIdx.y * 64;
    int kbase = blockIdx.z * NK * 32;

    __shared__ __align__(16) unsigned short a_lds[64 * 40];
    __shared__ __align__(16) unsigned short b_lds[64 * 40];

    f32x4 acc00 = {0,0,0,0}, acc01 = {0,0,0,0}, acc10 = {0,0,0,0}, acc11 = {0,0,0,0};

    int srow = tid >> 2, sseg = tid & 3;
    const int4* gA = (const int4*)(A + (size_t)(m0 + srow) * MLP_IN + kbase + sseg * 8);
    int lwsA = srow * 40 + sseg * 8;

    int bcol = tid & 63, bkg = tid >> 6;
    const float* gW = W1 + (size_t)(kbase + bkg * 8) * MLP_HID + n0 + bcol;
    int lwsB = bcol * 40 + bkg * 8;

    int a_off = (wr + (lane & 15)) * 40 + (lane >> 4) * 8;
    int b_off = (wc + (lane & 15)) * 40 + (lane >> 4) * 8;

    int4 ra = gA[0];
    float rfv[8];
#pragma unroll
    for (int i = 0; i < 8; ++i) rfv[i] = gW[(size_t)i * MLP_HID];

    for (int kk = 0; kk < NK; ++kk) {
        *(int4*)&a_lds[lwsA] = ra;
        union { unsigned short us[8]; int4 v; } pk;
#pragma unroll
        for (int i = 0; i < 8; ++i) pk.us[i] = f2b(rfv[i]);
        *(int4*)&b_lds[lwsB] = pk.v;
        __syncthreads();
        if (kk + 1 < NK) {
            ra = gA[(kk + 1) * 4];
            const float* g2 = gW + (size_t)(kk + 1) * 32 * MLP_HID;
#pragma unroll
            for (int i = 0; i < 8; ++i) rfv[i] = g2[(size_t)i * MLP_HID];
        }
        bf16x8 a0 = *(const bf16x8*)&a_lds[a_off];
        bf16x8 a1 = *(const bf16x8*)&a_lds[a_off + 16 * 40];
        bf16x8 b0 = *(const bf16x8*)&b_lds[b_off];
        bf16x8 b1 = *(const bf16x8*)&b_lds[b_off + 16 * 40];
        acc00 = __builtin_amdgcn_mfma_f32_16x16x32_bf16(a0, b0, acc00, 0, 0, 0);
        acc01 = __builtin_amdgcn_mfma_f32_16x16x32_bf16(a0, b1, acc01, 0, 0, 0);
        acc10 = __builtin_amdgcn_mfma_f32_16x16x32_bf16(a1, b0, acc10, 0, 0, 0);
        acc11 = __builtin_amdgcn_mfma_f32_16x16x32_bf16(a1, b1, acc11, 0, 0, 0);
        __syncthreads();
    }

    int crow = (lane >> 4) * 4, ccol = lane & 15;
    int row0 = m0 + wr + crow, row1 = row0 + 16;
    int col0 = n0 + wc + ccol, col1 = col0 + 16;
    unsigned short* dst = partial + (size_t)blockIdx.z * 256 * MLP_HID;
#pragma unroll
    for (int r = 0; r < 4; ++r) {
        dst[(size_t)(row0 + r) * MLP_HID + col0] = f2b(acc00[r]);
        dst[(size_t)(row0 + r) * MLP_HID + col1] = f2b(acc01[r]);
        dst[(size_t)(row1 + r) * MLP_HID + col0] = f2b(acc10[r]);
        dst[(size_t)(row1 + r) * MLP_HID + col1] = f2b(acc11[r]);
    }
}

// ---------------- generic bf16 MFMA GEMM (head) [r7 verbatim] ----------------
template<int MODE>
__global__ __launch_bounds__(256) void k_gemm(const unsigned short* __restrict__ A,
        const unsigned short* __restrict__ Bt, void* __restrict__ Cout,
        int K, int nk, int ldc) {
    int tid = threadIdx.x;
    int lane = tid & 63, wv = tid >> 6;
    int wr = (wv >> 1) * 32, wc = (wv & 1) * 32;
    int n0 = blockIdx.x * 64, m0 = blockIdx.y * 64;
    size_t kbase = (size_t)blockIdx.z * nk * 32;

    __shared__ __align__(16) unsigned short a_lds[64 * 40];
    __shared__ __align__(16) unsigned short b_lds[64 * 40];

    f32x4 acc00 = {0,0,0,0}, acc01 = {0,0,0,0}, acc10 = {0,0,0,0}, acc11 = {0,0,0,0};

    int srow = tid >> 2, sseg = tid & 3;
    const int4* gA = (const int4*)(A + (size_t)(m0 + srow) * K + kbase + sseg * 8);
    const int4* gB = (const int4*)(Bt + (size_t)(n0 + srow) * K + kbase + sseg * 8);
    int lws = srow * 40 + sseg * 8;

    int a_off = (wr + (lane & 15)) * 40 + (lane >> 4) * 8;
    int b_off = (wc + (lane & 15)) * 40 + (lane >> 4) * 8;

    int4 ra = gA[0], rb = gB[0];
    for (int kk = 0; kk < nk; ++kk) {
        *(int4*)&a_lds[lws] = ra;
        *(int4*)&b_lds[lws] = rb;
        __syncthreads();
        if (kk + 1 < nk) { ra = gA[(kk + 1) * 4]; rb = gB[(kk + 1) * 4]; }
        bf16x8 a0 = *(const bf16x8*)&a_lds[a_off];
        bf16x8 a1 = *(const bf16x8*)&a_lds[a_off + 16 * 40];
        bf16x8 b0 = *(const bf16x8*)&b_lds[b_off];
        bf16x8 b1 = *(const bf16x8*)&b_lds[b_off + 16 * 40];
        acc00 = __builtin_amdgcn_mfma_f32_16x16x32_bf16(a0, b0, acc00, 0, 0, 0);
        acc01 = __builtin_amdgcn_mfma_f32_16x16x32_bf16(a0, b1, acc01, 0, 0, 0);
        acc10 = __builtin_amdgcn_mfma_f32_16x16x32_bf16(a1, b0, acc10, 0, 0, 0);
        acc11 = __builtin_amdgcn_mfma_f32_16x16x32_bf16(a1, b1, acc11, 0, 0, 0);
        __syncthreads();
    }

    int crow = (lane >> 4) * 4, ccol = lane & 15;
    int row0 = m0 + wr + crow, row1 = row0 + 16;
    int col0 = n0 + wc + ccol, col1 = col0 + 16;
    float* dst = (float*)Cout + (size_t)blockIdx.z * (gridDim.y * 64) * ldc;
#pragma unroll
    for (int r = 0; r < 4; ++r) {
        dst[(size_t)(row0 + r) * ldc + col0] = acc00[r];
        dst[(size_t)(row0 + r) * ldc + col1] = acc01[r];
        dst[(size_t)(row1 + r) * ldc + col0] = acc10[r];
        dst[(size_t)(row1 + r) * ldc + col1] = acc11[r];
    }
}

// ---------------- reduce bf16 partials + bias + relu -> bf16 hidden [vectorized] ----------------
// 128 blocks x 256 thr; thread handles 8 consecutive elems via bf16x8 loads
__global__ void k_mred(const unsigned short* __restrict__ partial, const float* __restrict__ b1,
                       unsigned short* __restrict__ hiddenb) {
    int base = (blockIdx.x * 256 + threadIdx.x) * 8;   // < 256*1024
    const float4* bb = (const float4*)(b1 + (base & (MLP_HID - 1)));
    float4 bv0 = bb[0], bv1 = bb[1];
    float s[8] = {bv0.x, bv0.y, bv0.z, bv0.w, bv1.x, bv1.y, bv1.z, bv1.w};
#pragma unroll
    for (int z = 0; z < NCH; ++z) {
        bf16x8 p = *(const bf16x8*)&partial[(size_t)z * 256 * MLP_HID + base];
#pragma unroll
        for (int i = 0; i < 8; ++i) s[i] += b2f((unsigned short)p[i]);
    }
    union { unsigned short us[8]; int4 v; } pk;
#pragma unroll
    for (int i = 0; i < 8; ++i) pk.us[i] = f2b(fmaxf(s[i], 0.f));
    *(int4*)&hiddenb[base] = pk.v;
}

// ---------------- finalize: reduce head partials + postprocess [r7 verbatim] ----------------
__global__ __launch_bounds__(128) void k_fin(const float* __restrict__ partial2,
        const float* __restrict__ b2, const float* __restrict__ A,
        const float* __restrict__ x_mod, float* __restrict__ outp) {
    int b = blockIdx.x;
    int tid = threadIdx.x;
    __shared__ float o[OUTD];
    __shared__ float gt[M], vv[V], pfc[M], qfc[M];

    if (tid < OUTD) {
        float s = b2[tid];
#pragma unroll
        for (int z = 0; z < 4; ++z) s += partial2[(size_t)z * 256 * 128 + b * 128 + tid];
        o[tid] = s;
    }
    __syncthreads();

    if (tid < M) {
        float g = (tid < M - NSW) ? 1.0f : sigmoidf(o[M + V + (tid - (M - NSW))]);
        gt[tid] = g;
        pfc[tid] = g * o[tid];
    }
    if (tid < V) vv[tid] = (tid == 0) ? 1.0f : o[M + tid];
    __syncthreads();

    if (tid < M) {
        float acc = 0.f;
        for (int xx = 0; xx < V; ++xx) acc += vv[xx] * A[xx * M + tid];
        qfc[tid] = gt[tid] * acc;
    }
    __syncthreads();

    float* zb = outp + (size_t)b * ZDIM;
    if (tid < M) zb[tid] = pfc[tid];
    if (tid < V) zb[M + tid] = vv[tid];
    if (tid < M) zb[M + V + tid] = gt[tid];

    float* zcb = outp + (size_t)B * ZDIM + (size_t)b * ZCDIM;
    if (tid < M) zcb[tid] = qfc[tid];
    if (tid < V) {
        float accp = 0.f, accq = 0.f;
        for (int mm = 0; mm < M; ++mm) {
            float a = A[tid * M + mm];
            accp += a * pfc[mm];
            accq += a * qfc[mm];
        }
        zcb[M + tid]     = x_mod[(size_t)(b * V + tid) * FIN + 0] + accp;
        zcb[M + V + tid] = x_mod[(size_t)(b * V + tid) * FIN + 1] + accq;
    }
}

extern "C" void kernel_launch(void* const* d_in, const int* in_sizes, int n_in,
                              void* d_out, int out_size, void* d_ws, size_t ws_size,
                              hipStream_t stream) {
    const float* x_mod = (const float*)d_in[0];
    const int*   ei    = (const int*)d_in[1];
    const int*   si    = (const int*)d_in[2];
    const float* Ainc  = (const float*)d_in[3];
    const float* embed = (const float*)d_in[4];
    const float* WU0   = (const float*)d_in[5];
    const float* WV0   = (const float*)d_in[6];
    const float* WA0   = (const float*)d_in[7];
    const float* WB0   = (const float*)d_in[8];
    const float* WC0   = (const float*)d_in[9];
    const float* WU1   = (const float*)d_in[10];
    const float* WV1   = (const float*)d_in[11];
    const float* WA1   = (const float*)d_in[12];
    const float* WB1   = (const float*)d_in[13];
    const float* WC1   = (const float*)d_in[14];
    const float* W1    = (const float*)d_in[15];
    const float* b1    = (const float*)d_in[16];
    const float* W2    = (const float*)d_in[17];
    const float* b2    = (const float*)d_in[18];
    float* out = (float*)d_out;

    // Workspace layout (byte offsets), ~11.7 MB
    char* ws = (char*)d_ws;
    unsigned short* W0t      = (unsigned short*)(ws + 0);          //    32,768
    unsigned short* Wt640    = (unsigned short*)(ws + 32768);      //   163,840
    unsigned short* W2t      = (unsigned short*)(ws + 196608);     //   262,144
    unsigned short* Abf      = (unsigned short*)(ws + 458752);     // 3,407,872 (rows >=200 stale, benign)
    unsigned short* partialM = (unsigned short*)(ws + 3866624);    // 6,815,744 (bf16, 13 chunks)
    unsigned short* hiddenb  = (unsigned short*)(ws + 10682368);   //   524,288
    float*          partial2 = (float*)(ws + 11206656);            //   524,288

    // 1. small weight prep (W0t, Wt640, W2t)
    k_prep<<<112, 256, 0, stream>>>(WU0, WV0, WB0, WC0, WU1, WV1, WB1, WC1, WA1, W2,
                                    W0t, Wt640, W2t);
    // 2. fully fused GNN (both layers, MFMA projections) -> Abf
    k_gnn<<<B, 512, 0, stream>>>(x_mod, ei, si, embed, WA0, W0t, Wt640, Abf);
    // 3. MLP hidden: (256x6656) @ W1 (f32, on-the-fly transpose), split-K=13, bf16 partials
    k_mlp<<<dim3(16, 4, NCH), 256, 0, stream>>>(Abf, W1, partialM);
    // 4. reduce (vectorized bf16) + bias + relu -> hiddenb bf16
    k_mred<<<128, 256, 0, stream>>>(partialM, b1, hiddenb);
    // 5. head GEMM: (256x1024) @ (1024x128), split-K=4 -> partial2
    k_gemm<2><<<dim3(2, 4, 4), 256, 0, stream>>>(hiddenb, W2t, partial2, MLP_HID, 8, 128);
    // 6. finalize: reduce + graph postprocess
    k_fin<<<B, 128, 0, stream>>>(partial2, b2, Ainc, x_mod, out);
}